// Round 12
// baseline (1458.147 us; speedup 1.0000x reference)
//
#include <hip/hip_runtime.h>
#include <hip/hip_bf16.h>

#define NEG 0.2f
#define LRELU(x) ((x) > 0.f ? (x) : NEG*(x))

typedef __hip_bfloat16 bf16;
typedef __attribute__((ext_vector_type(8))) short short8v;  // 8 bf16 (4 VGPRs)
typedef __attribute__((ext_vector_type(4))) float f32x4;

__device__ __forceinline__ float b2f(bf16 v){ return __bfloat162float(v); }

__device__ __forceinline__ float wred(float v){
#pragma unroll
  for(int o=32;o>0;o>>=1) v += __shfl_down(v,o);
  return v; // valid at lane 0
}

__device__ __forceinline__ int atomAddI(int* p, int v){
  return __hip_atomic_fetch_add(p, v, __ATOMIC_RELAXED, __HIP_MEMORY_SCOPE_AGENT);
}

// ---------------- one-time prep: CSR by dst, node-type sort, B-fragments ----------------

__global__ __launch_bounds__(256) void k_hist(
    const int* __restrict__ dst, int* __restrict__ deg, int nE)
{
  int e = blockIdx.x*blockDim.x + threadIdx.x;
  if (e >= nE) return;
  atomAddI(&deg[dst[e]], 1);
}

__global__ __launch_bounds__(1024) void k_scan(
    const int* __restrict__ deg, int* __restrict__ off, int nN)
{
  __shared__ int part[1024];
  int tid = threadIdx.x;
  int chunk = (nN + 1023) / 1024;
  int lo = tid*chunk, hi = min((tid+1)*chunk, nN);
  int s = 0;
  for (int i=lo;i<hi;i++) s += deg[i];
  part[tid] = s;
  __syncthreads();
  for (int d=1; d<1024; d<<=1){
    int v = (tid>=d) ? part[tid-d] : 0;
    __syncthreads();
    part[tid] += v;
    __syncthreads();
  }
  int run = (tid==0) ? 0 : part[tid-1];
  for (int i=lo;i<hi;i++){ off[i] = run; run += deg[i]; }
  if (tid==1023) off[nN] = part[1023];
}

__global__ __launch_bounds__(256) void k_scatter(
    const int* __restrict__ dst, const int* __restrict__ off,
    int* __restrict__ cnt, int* __restrict__ eid, int nE)
{
  int e = blockIdx.x*blockDim.x + threadIdx.x;
  if (e >= nE) return;
  int d = dst[e];
  int p = atomAddI(&cnt[d], 1);
  eid[off[d] + p] = e;
}

__global__ __launch_bounds__(256) void k_perm(
    const int* __restrict__ eid, const int* __restrict__ src,
    const int* __restrict__ dst, const int* __restrict__ ety,
    int* __restrict__ srcP, int* __restrict__ dstP, int* __restrict__ etyP, int nE)
{
  int i = blockIdx.x*blockDim.x + threadIdx.x;
  if (i >= nE) return;
  int e = eid[i];
  srcP[i] = src[e];
  dstP[i] = dst[e];
  etyP[i] = ety[e];
}

// node-type sort: 3-bin histogram, padded-to-32 offsets, scatter
__global__ __launch_bounds__(256) void k_nhist(
    const int* __restrict__ ntype, int* __restrict__ ndeg, int nN)
{
  int n = blockIdx.x*blockDim.x + threadIdx.x;
  if (n >= nN) return;
  atomAddI(&ndeg[ntype[n]], 1);
}

__global__ void k_npad(const int* __restrict__ ndeg, int* __restrict__ poffPad)
{
  if (threadIdx.x==0 && blockIdx.x==0){
    int o = 0;
#pragma unroll
    for (int t=0;t<3;t++){ poffPad[t] = o; o += ((ndeg[t]+31)/32)*32; }
    poffPad[3] = o;
  }
}

__global__ __launch_bounds__(256) void k_nscatter(
    const int* __restrict__ ntype, const int* __restrict__ poffPad,
    int* __restrict__ ncnt, int* __restrict__ nPermPad, int nN)
{
  int n = blockIdx.x*blockDim.x + threadIdx.x;
  if (n >= nN) return;
  int t = ntype[n];
  int p = atomAddI(&ncnt[t], 1);
  nPermPad[poffPad[t] + p] = n;
}

// ---- unified B-fragment builder ----
// frag[((nt*KS+ks)*64+lane)*8+j] = B[ks*32+kb*8+j][nt*16+col16]
// nt<4: B = W (f32 [K][64]); nt==4 (NT==5): col16==0 -> (W @ Wi)[k], col16==1 -> (W @ Wj)[k], else 0
struct BDesc { const float* W; const float* Wi; const float* Wj; int KS; int NT; int dstOff; };
struct PrepArgs {
  BDesc d[15];
  const float* bhl[3];
  const float* watt[3];
};

__global__ __launch_bounds__(256) void k_prep(
    PrepArgs pa, bf16* __restrict__ fragBase, float* __restrict__ biasDot)
{
  int bid = blockIdx.x;
  if (bid < 75){
    int b = bid / 5;
    int tid = (bid % 5)*256 + threadIdx.x;
    BDesc d = pa.d[b];
    int total = d.NT * d.KS * 64;
    if (tid >= total) return;
    int lane = tid & 63;
    int ks = (tid>>6) % d.KS;
    int nt = (tid>>6) / d.KS;
    int kb = lane>>4, col16 = lane&15;
    bf16* frag = fragBase + d.dstOff;
#pragma unroll
    for (int j=0;j<8;j++){
      int k = ks*32 + kb*8 + j;
      float val;
      if (nt < 4) val = d.W[k*64 + nt*16 + col16];
      else {
        const float* v = (col16==0) ? d.Wi : (col16==1) ? d.Wj : nullptr;
        val = 0.f;
        if (v){ for (int c=0;c<64;c++) val = fmaf(d.W[k*64+c], v[c], val); }
      }
      frag[((size_t)(nt*d.KS+ks)*64 + lane)*8 + j] = __float2bfloat16(val);
    }
  } else {
    // biasDot[L*6 + t*2 + ij] = bhl[L][t] . Watt[L][ij*64 : ij*64+64]
    int lane = threadIdx.x;
    if (lane >= 64) return;
    for (int idx=0; idx<18; idx++){
      int L = idx/6, rem = idx%6, t = rem>>1, ij = rem&1;
      float p = pa.bhl[L][t*64 + lane] * pa.watt[L][ij*64 + lane];
      p = wred(p);
      if (lane==0) biasDot[idx] = p;
    }
  }
}

// ---------------- per-layer kernels ----------------

// MFMA hetero node transform on TYPE-SORTED padded nodes; 32 nodes/wave (2 tiles).
// h[orig] = xin[orig]@Whl[t] + bhl[t]  (bf16); hi_s/hj_s via folded B-cols 64/65 (+ bias-dot).
template<bool RELU_IN>
__global__ __launch_bounds__(256) void k_hlin_mfma(
    const float* __restrict__ xin, const int* __restrict__ nPermPad,
    const int* __restrict__ poffPad, const bf16* __restrict__ hlFragL,
    const float* __restrict__ bhl, const float* __restrict__ biasDotL,
    bf16* __restrict__ h, float* __restrict__ hi_s, float* __restrict__ hj_s)
{
  int wid  = (blockIdx.x*blockDim.x + threadIdx.x) >> 6;
  int lane = threadIdx.x & 63;
  int n0 = wid * 32;
  if (n0 >= poffPad[3]) return;
  int t = (n0 >= poffPad[1]) + (n0 >= poffPad[2]);
  const bf16* frag = hlFragL + (size_t)t*5120;   // 5nt*2ks*64*8
  int row = lane & 15, kb = lane >> 4;

  // A fragments (f32 rows -> bf16), gathered via nPermPad
  short8v a[2][2];
#pragma unroll
  for (int tl=0; tl<2; tl++){
    int orig = nPermPad[n0 + tl*16 + row];
    const float* p = xin + (size_t)max(orig,0)*64;
#pragma unroll
    for (int ks=0; ks<2; ks++){
#pragma unroll
      for (int j=0;j<8;j++){
        float v = p[ks*32 + kb*8 + j];
        if (RELU_IN) v = fmaxf(v, 0.f);
        bf16 b = __float2bfloat16(v);
        a[tl][ks][j] = *reinterpret_cast<short*>(&b);
      }
    }
  }

  f32x4 acc[2][5];
#pragma unroll
  for (int nt=0; nt<5; nt++){
    f32x4 c0 = {0.f,0.f,0.f,0.f}, c1 = {0.f,0.f,0.f,0.f};
#pragma unroll
    for (int ks=0; ks<2; ks++){
      short8v b = *reinterpret_cast<const short8v*>(
          reinterpret_cast<const short*>(frag) + (((size_t)nt*2 + ks)*64 + lane)*8);
      c0 = __builtin_amdgcn_mfma_f32_16x16x32_bf16(a[0][ks], b, c0, 0, 0, 0);
      c1 = __builtin_amdgcn_mfma_f32_16x16x32_bf16(a[1][ks], b, c1, 0, 0, 0);
    }
    acc[0][nt] = c0; acc[1][nt] = c1;
  }

  float bb[4];
#pragma unroll
  for (int nt=0;nt<4;nt++) bb[nt] = bhl[t*64 + nt*16 + row];
  float bdi = biasDotL[t*2+0], bdj = biasDotL[t*2+1];

#pragma unroll
  for (int tl=0; tl<2; tl++){
#pragma unroll
    for (int r=0;r<4;r++){
      int orig = nPermPad[n0 + tl*16 + kb*4 + r];
      if (orig >= 0){
#pragma unroll
        for (int nt=0;nt<4;nt++)
          h[(size_t)orig*64 + nt*16 + row] = __float2bfloat16(acc[tl][nt][r] + bb[nt]);
        if (row==0) hi_s[orig] = acc[tl][4][r] + bdi;
        if (row==1) hj_s[orig] = acc[tl][4][r] + bdj;
      }
    }
  }
}

// MFMA edge transform, DST-SORTED storage, 32 edges/wave. Pure GEMM + lp partial.
// eaS[i,:] = lrelu((relu?)ain[i,:] @ Wea); lp[i] = eaS_acc . Watt[132:196]
// LAYER==2: e_out[eid[i]] = relu(acc).Wec[etyP[i]] + bec
template<int LAYER>
__global__ __launch_bounds__(256) void k_ea_mfma(
    const void* __restrict__ ain_, const int* __restrict__ eid,
    const bf16* __restrict__ bfrag, const float* __restrict__ Watt,
    const int* __restrict__ etyP,
    bf16* __restrict__ eaS, float* __restrict__ lp,
    const float* __restrict__ Wec, const float* __restrict__ bec,
    float* __restrict__ e_out, int nE)
{
  constexpr int KS = (LAYER==0) ? 1 : 2;
  int wid  = (blockIdx.x*blockDim.x + threadIdx.x) >> 6;
  int lane = threadIdx.x & 63;
  int e0 = wid * 32;
  if (e0 >= nE) return;
  int row = lane & 15;
  int kb  = lane >> 4;

  short8v a[2][KS];
#pragma unroll
  for (int tl=0; tl<2; tl++){
    int er = min(e0 + tl*16 + row, nE-1);
    if (LAYER==0) {
      const float* A = (const float*)ain_;
      const float* p = A + (size_t)eid[er]*32 + kb*8;
#pragma unroll
      for (int j=0;j<8;j++){
        bf16 b = __float2bfloat16(p[j]);
        a[tl][0][j] = *reinterpret_cast<short*>(&b);
      }
    } else {
      const bf16* A = (const bf16*)ain_;
#pragma unroll
      for (int ks=0; ks<KS; ks++){
        short8v v = *reinterpret_cast<const short8v*>(
            reinterpret_cast<const short*>(A + (size_t)er*64 + ks*32 + kb*8));
#pragma unroll
        for (int j=0;j<8;j++) v[j] = (v[j] & (short)0x8000) ? (short)0 : v[j];
        a[tl][ks] = v;
      }
    }
  }

  f32x4 acc[2][4];
#pragma unroll
  for (int nt=0; nt<4; nt++){
    f32x4 c0 = {0.f,0.f,0.f,0.f}, c1 = {0.f,0.f,0.f,0.f};
#pragma unroll
    for (int ks=0; ks<KS; ks++){
      short8v b = *reinterpret_cast<const short8v*>(
          reinterpret_cast<const short*>(bfrag) + (((size_t)nt*KS + ks)*64 + lane)*8);
      c0 = __builtin_amdgcn_mfma_f32_16x16x32_bf16(a[0][ks], b, c0, 0, 0, 0);
      c1 = __builtin_amdgcn_mfma_f32_16x16x32_bf16(a[1][ks], b, c1, 0, 0, 0);
    }
#pragma unroll
    for (int r=0;r<4;r++){ c0[r] = LRELU(c0[r]); c1[r] = LRELU(c1[r]); }
    acc[0][nt] = c0; acc[1][nt] = c1;
  }

#pragma unroll
  for (int tl=0; tl<2; tl++){
#pragma unroll
    for (int r=0;r<4;r++){
      int e = e0 + tl*16 + kb*4 + r;
      if (e < nE){
#pragma unroll
        for (int nt=0;nt<4;nt++)
          eaS[(size_t)e*64 + nt*16 + row] = __float2bfloat16(acc[tl][nt][r]);
      }
    }
  }

  // lp partial (+ e_out for LAYER==2)
#pragma unroll
  for (int tl=0; tl<2; tl++){
#pragma unroll
    for (int r=0;r<4;r++){
      int e = e0 + tl*16 + kb*4 + r;
      bool valid = (e < nE);
      float lpv = 0.f, pe = 0.f;
      int t = 0;
      if (LAYER==2) t = valid ? etyP[e] : 0;
#pragma unroll
      for (int nt=0;nt<4;nt++){
        lpv = fmaf(acc[tl][nt][r], Watt[132 + nt*16 + row], lpv);
        if (LAYER==2) pe = fmaf(fmaxf(acc[tl][nt][r],0.f), Wec[t*64 + nt*16 + row], pe);
      }
#pragma unroll
      for (int m=1;m<16;m<<=1){
        lpv += __shfl_xor(lpv, m);
        if (LAYER==2) pe += __shfl_xor(pe, m);
      }
      if (row == 0 && valid){
        lp[e] = lpv;
        if (LAYER==2) e_out[eid[e]] = pe + bec[t];
      }
    }
  }
}

// thread-per-edge attention: exS[e] = exp(lrelu(lp[e] + hi_s[d] + hj_s[s] + wt))  (in-place on lp)
__global__ __launch_bounds__(256) void k_att(
    const int* __restrict__ srcP, const int* __restrict__ dstP,
    const int* __restrict__ etyP, const float* __restrict__ Ete,
    const float* __restrict__ Watt,
    const float* __restrict__ hi_s, const float* __restrict__ hj_s,
    float* __restrict__ lpex, int nE)
{
  int e = blockIdx.x*blockDim.x + threadIdx.x;
  if (e >= nE) return;
  int d = dstP[e], s = srcP[e], t = etyP[e];
  float wt = 0.f;
#pragma unroll
  for (int k=0;k<4;k++){ float v = Ete[t*4+k]; v = LRELU(v); wt = fmaf(v, Watt[128+k], wt); }
  float l = lpex[e] + hi_s[d] + hj_s[s] + wt;
  l = LRELU(l);
  lpex[e] = __expf(fminf(l, 60.f));
}

// Streaming CSR aggregation (sorted edges), 2 edges/iter.
__global__ __launch_bounds__(256) void k_agg(
    const int* __restrict__ off, const int* __restrict__ srcP,
    const bf16* __restrict__ h, const bf16* __restrict__ eaS,
    const float* __restrict__ exS,
    bf16* __restrict__ uv, int nN)
{
  int wid  = (blockIdx.x*blockDim.x + threadIdx.x) >> 6;
  int lane = threadIdx.x & 63;
  if (wid >= nN) return;
  int beg = off[wid], end = off[wid+1];
  float au = 0.f, av = 0.f, ss = 0.f;
  int i = beg;
  for (; i+1 < end; i += 2){
    int   s0 = srcP[i],   s1 = srcP[i+1];
    float a0 = exS[i],    a1 = exS[i+1];
    float h0 = b2f(h[(size_t)s0*64 + lane]);
    float h1 = b2f(h[(size_t)s1*64 + lane]);
    float v0 = b2f(eaS[(size_t)i*64 + lane]);
    float v1 = b2f(eaS[(size_t)(i+1)*64 + lane]);
    au = fmaf(a0, h0, au); av = fmaf(a0, v0, av); ss += a0;
    au = fmaf(a1, h1, au); av = fmaf(a1, v1, av); ss += a1;
  }
  if (i < end){
    int s = srcP[i]; float a = exS[i];
    au = fmaf(a, b2f(h[(size_t)s*64 + lane]), au);
    av = fmaf(a, b2f(eaS[(size_t)i*64 + lane]), av);
    ss += a;
  }
  float inv = 1.f / (ss + 1e-16f);
  uv[(size_t)wid*128 + lane]      = __float2bfloat16(au * inv);
  uv[(size_t)wid*128 + 64 + lane] = __float2bfloat16(av * inv);
}

// MFMA node matmul: out[n] = uv[n,0:128] @ Wlin. FINAL: fuse x_out = relu(out).Wnc[t]+bnc[t].
template<bool FINAL>
__global__ __launch_bounds__(256) void k_mm_mfma(
    const bf16* __restrict__ uv, const bf16* __restrict__ bfrag,
    float* __restrict__ out,
    const int* __restrict__ ntype, const float* __restrict__ Wnc,
    const float* __restrict__ bnc, float* __restrict__ xout, int nN)
{
  int wid  = (blockIdx.x*blockDim.x + threadIdx.x) >> 6;
  int lane = threadIdx.x & 63;
  int n0 = wid * 16;
  if (n0 >= nN) return;
  int row = lane & 15;
  int kb  = lane >> 4;
  int nr  = min(n0 + row, nN-1);

  short8v a[4];
#pragma unroll
  for (int ks=0; ks<4; ks++)
    a[ks] = *reinterpret_cast<const short8v*>(
        reinterpret_cast<const short*>(uv + (size_t)nr*128 + ks*32 + kb*8));

  f32x4 acc[4];
#pragma unroll
  for (int nt=0; nt<4; nt++){
    f32x4 c = {0.f,0.f,0.f,0.f};
#pragma unroll
    for (int ks=0; ks<4; ks++){
      short8v b = *reinterpret_cast<const short8v*>(
          reinterpret_cast<const short*>(bfrag) + (((size_t)nt*4 + ks)*64 + lane)*8);
      c = __builtin_amdgcn_mfma_f32_16x16x32_bf16(a[ks], b, c, 0, 0, 0);
    }
    acc[nt] = c;
  }

  if (!FINAL){
#pragma unroll
    for (int r=0;r<4;r++){
      int n = n0 + kb*4 + r;
      if (n < nN){
#pragma unroll
        for (int nt=0;nt<4;nt++)
          out[(size_t)n*64 + nt*16 + row] = acc[nt][r];
      }
    }
  } else {
#pragma unroll
    for (int r=0;r<4;r++){
      int n = n0 + kb*4 + r;
      bool valid = (n < nN);
      int t = valid ? ntype[n] : 0;
      float pe = 0.f;
#pragma unroll
      for (int nt=0;nt<4;nt++)
        pe = fmaf(fmaxf(acc[nt][r],0.f), Wnc[t*64 + nt*16 + row], pe);
#pragma unroll
      for (int m=1;m<16;m<<=1) pe += __shfl_xor(pe, m);
      if (row == 0 && valid) xout[n] = pe + bnc[t];
    }
  }
}

extern "C" void kernel_launch(void* const* d_in, const int* in_sizes, int n_in,
                              void* d_out, int out_size, void* d_ws, size_t ws_size,
                              hipStream_t stream) {
  const float* x      = (const float*)d_in[0];
  const int*   eidx   = (const int*) d_in[1];
  const int*   ntype  = (const int*) d_in[2];
  const int*   etype  = (const int*) d_in[3];
  const float* eattr  = (const float*)d_in[4];
  const float* Whl[3]  = {(const float*)d_in[5],  (const float*)d_in[11], (const float*)d_in[17]};
  const float* bhl[3]  = {(const float*)d_in[6],  (const float*)d_in[12], (const float*)d_in[18]};
  const float* Ete[3]  = {(const float*)d_in[7],  (const float*)d_in[13], (const float*)d_in[19]};
  const float* Wea[3]  = {(const float*)d_in[8],  (const float*)d_in[14], (const float*)d_in[20]};
  const float* Watt[3] = {(const float*)d_in[9],  (const float*)d_in[15], (const float*)d_in[21]};
  const float* Wlin[3] = {(const float*)d_in[10], (const float*)d_in[16], (const float*)d_in[22]};
  const float* Wnc = (const float*)d_in[23];
  const float* bnc = (const float*)d_in[24];
  const float* Wec = (const float*)d_in[25];
  const float* bec = (const float*)d_in[26];

  const int nN = in_sizes[2];      // 50000
  const int nE = in_sizes[3];      // 800000
  const int* srcI = eidx;
  const int* dstI = eidx + nE;

  // workspace layout (f32 words)
  float* ws = (float*)d_ws;
  size_t o = 0;
  bf16*  h      = (bf16*)(ws + o); o += (size_t)nN*32;   // [N][64] bf16
  float* outA   = ws + o;                                 // [N][64] f32, ALIASES uv
  bf16*  uv     = (bf16*)(ws + o); o += (size_t)nN*64;   // [N][128] bf16
  float* hi_s   = ws + o;          o += (size_t)nN;
  float* hj_s   = ws + o;          o += (size_t)nN;
  float* lpex   = ws + o;          o += (size_t)nE;      // lp -> exp, sorted order
  bf16*  eaS    = (bf16*)(ws + o); o += (size_t)nE*32;   // [E][64] bf16, SORTED
  int*   deg    = (int*)(ws + o);  o += (size_t)nN;
  int*   off    = (int*)(ws + o);  o += (size_t)nN + 1;
  int*   eid    = (int*)(ws + o);  o += (size_t)nE;
  int*   srcP   = (int*)(ws + o);  o += (size_t)nE;
  int*   dstP   = (int*)(ws + o);  o += (size_t)nE;
  int*   etyP   = (int*)(ws + o);  o += (size_t)nE;
  int*   ndeg   = (int*)(ws + o);  o += 4;
  int*   ncnt   = (int*)(ws + o);  o += 4;
  int*   poffPad= (int*)(ws + o);  o += 4;
  int*   nPermPad=(int*)(ws + o);  o += (size_t)nN + 96;
  o = (o + 3) & ~(size_t)3;                              // 16B align
  bf16*  fragB  = (bf16*)(ws + o); o += 40448;           // 80896 bf16
  float* biasDot= ws + o;          o += 18;

  // frag offsets (bf16 units)
  const int eaOff[3] = {0, 2048, 6144};
  const int hlOff = 10240;            // + (L*3+t)*5120
  const int wlOff = 56320;            // + L*8192

  dim3 blk(256);
  int nodeWB = (int)(((size_t)nN*64 + 255)/256);
  int edgeTB = (nE + 255)/256;
  int nodeTB = (nN + 255)/256;
  int eaMB   = (int)(((size_t)((nE+31)/32)*64 + 255)/256);
  int hlMB   = (int)(((size_t)((nN+96+31)/32)*64 + 255)/256);
  int mmMB   = (int)(((size_t)((nN+15)/16)*64 + 255)/256);

  // ---- one-time prep ----
  hipMemsetAsync(deg, 0, (size_t)nN*4, stream);
  k_hist<<<edgeTB, blk, 0, stream>>>(dstI, deg, nE);
  k_scan<<<1, 1024, 0, stream>>>(deg, off, nN);
  hipMemsetAsync(deg, 0, (size_t)nN*4, stream);
  k_scatter<<<edgeTB, blk, 0, stream>>>(dstI, off, deg, eid, nE);
  k_perm<<<edgeTB, blk, 0, stream>>>(eid, srcI, dstI, etype, srcP, dstP, etyP, nE);

  hipMemsetAsync(ndeg, 0, 8*4, stream);                   // ndeg + ncnt
  k_nhist<<<nodeTB, blk, 0, stream>>>(ntype, ndeg, nN);
  k_npad<<<1, 64, 0, stream>>>(ndeg, poffPad);
  hipMemsetAsync(nPermPad, 0xFF, ((size_t)nN+96)*4, stream);
  k_nscatter<<<nodeTB, blk, 0, stream>>>(ntype, poffPad, ncnt, nPermPad, nN);

  PrepArgs pa;
  pa.d[0] = {Wea[0], nullptr, nullptr, 1, 4, eaOff[0]};
  pa.d[1] = {Wea[1], nullptr, nullptr, 2, 4, eaOff[1]};
  pa.d[2] = {Wea[2], nullptr, nullptr, 2, 4, eaOff[2]};
  for (int L=0; L<3; L++)
    for (int t=0; t<3; t++)
      pa.d[3 + L*3 + t] = {Whl[L] + (size_t)t*4096, Watt[L], Watt[L]+64, 2, 5, hlOff + (L*3+t)*5120};
  for (int L=0; L<3; L++)
    pa.d[12 + L] = {Wlin[L], nullptr, nullptr, 4, 4, wlOff + L*8192};
  for (int L=0; L<3; L++){ pa.bhl[L] = bhl[L]; pa.watt[L] = Watt[L]; }
  k_prep<<<76, blk, 0, stream>>>(pa, fragB, biasDot);

  float* xout = (float*)d_out;

  for (int L = 0; L < 3; ++L) {
    if (L == 0)
      k_hlin_mfma<false><<<hlMB, blk, 0, stream>>>(x,    nPermPad, poffPad, fragB + hlOff + L*3*5120,
                                                   bhl[L], biasDot + L*6, h, hi_s, hj_s);
    else
      k_hlin_mfma<true ><<<hlMB, blk, 0, stream>>>(outA, nPermPad, poffPad, fragB + hlOff + L*3*5120,
                                                   bhl[L], biasDot + L*6, h, hi_s, hj_s);

    if (L == 0)
      k_ea_mfma<0><<<eaMB, blk, 0, stream>>>(eattr, eid, fragB + eaOff[L], Watt[L], etyP,
                                             eaS, lpex, nullptr, nullptr, nullptr, nE);
    else if (L == 1)
      k_ea_mfma<1><<<eaMB, blk, 0, stream>>>(eaS, eid, fragB + eaOff[L], Watt[L], etyP,
                                             eaS, lpex, nullptr, nullptr, nullptr, nE);
    else
      k_ea_mfma<2><<<eaMB, blk, 0, stream>>>(eaS, eid, fragB + eaOff[L], Watt[L], etyP,
                                             eaS, lpex, Wec, bec, xout + nN, nE);

    k_att<<<edgeTB, blk, 0, stream>>>(srcP, dstP, etyP, Ete[L], Watt[L], hi_s, hj_s, lpex, nE);

    k_agg<<<nodeWB, blk, 0, stream>>>(off, srcP, h, eaS, lpex, uv, nN);

    if (L < 2)
      k_mm_mfma<false><<<mmMB, blk, 0, stream>>>(uv, fragB + wlOff + L*8192, outA,
                                                 nullptr, nullptr, nullptr, nullptr, nN);
    else
      k_mm_mfma<true ><<<mmMB, blk, 0, stream>>>(uv, fragB + wlOff + L*8192, nullptr,
                                                 ntype, Wnc, bnc, xout, nN);
  }
}